// Round 15
// baseline (66.681 us; speedup 1.0000x reference)
//
#include <hip/hip_runtime.h>

#define THREADS 256
typedef float v2f __attribute__((ext_vector_type(2)));

struct Params { const float* p[15]; };

// LDS float offsets/sizes, canonical order:
// W_fm b_fm W1 b1 Wp1 bp1 W2 b2 Wp2 bp2 W3 b3 protos Wh bh
__constant__ constexpr int k_offs[15]  = {0,128,144,400,416,608,620,716,724,756,760,776,780,820,834};
__constant__ constexpr int k_sizes[15] = {128,16,256,16,192,12,96,8,32,4,16,4,40,14,1};
#define W_TOTAL 835

// tanh(x) = 1 - 2/(exp(2x)+1), pk pair (R7 form — best measured)
__device__ __forceinline__ v2f tanh2(v2f x) {
    v2f xs = x * 2.885390081777927f;                // 2*log2(e)
    v2f e  = { __builtin_amdgcn_exp2f(xs.x),
               __builtin_amdgcn_exp2f(xs.y) };
    v2f ep = e + 1.0f;
    v2f r  = { __builtin_amdgcn_rcpf(ep.x),
               __builtin_amdgcn_rcpf(ep.y) };
    return (v2f){-2.0f, -2.0f} * r + 1.0f;
}

// R7 dense, weights from LDS: adjacent pair -> ds_read_b64, broadcast (no
// bank conflicts), VGPR-staged (frees the SGPR-starved s_load path).
template<int IN, int OUT>
__device__ __forceinline__ void dense(const float* x, float* y,
                                      const float* W, const float* b) {
#pragma unroll
    for (int j = 0; j < OUT; j += 2) {
        v2f acc = { b[j], b[j + 1] };
#pragma unroll
        for (int k = 0; k < IN; ++k) {
            v2f w = { W[k * OUT + j], W[k * OUT + j + 1] };
            acc += w * x[k];                        // v_pk_fma_f32
        }
        v2f t = tanh2(acc);
        y[j] = t.x; y[j + 1] = t.y;
    }
}

__global__ __launch_bounds__(THREADS) void qcnn_fused(
        const float* __restrict__ inputs, Params ps,
        float* __restrict__ out, int B) {
    __shared__ float sm[W_TOTAL];
#pragma unroll
    for (int p = 0; p < 15; ++p) {
        const float* src = ps.p[p];
        for (int i = threadIdx.x; i < k_sizes[p]; i += THREADS)
            sm[k_offs[p] + i] = src[i];
    }
    __syncthreads();

    const int tid = blockIdx.x * THREADS + threadIdx.x;
    if (tid >= B) return;

    float xa[16], xb[16];
    const float4* in4 = reinterpret_cast<const float4*>(inputs) + (size_t)tid * 2;
    float4 v0 = in4[0], v1 = in4[1];
    xa[0] = v0.x; xa[1] = v0.y; xa[2] = v0.z; xa[3] = v0.w;
    xa[4] = v1.x; xa[5] = v1.y; xa[6] = v1.z; xa[7] = v1.w;

    dense<8, 16>(xa, xb, sm + 0,   sm + 128);  // feature_map
    dense<16, 16>(xb, xa, sm + 144, sm + 400); // conv1
    dense<16, 12>(xa, xb, sm + 416, sm + 608); // pool1
    dense<12, 8>(xb, xa, sm + 620, sm + 716);  // conv2
    dense<8, 4>(xa, xb, sm + 724, sm + 756);   // pool2
    dense<4, 4>(xb, xa, sm + 760, sm + 776);   // conv3 -> xa[0..3]

    const float* protos = sm + 780;
    const float* Wh     = sm + 820;

    // head x-part, then RBF features vs 10 prototypes (GAMMA = 1)
    v2f ha = { sm[834], 0.0f };
    ha += (v2f){ xa[0], xa[1] } * (v2f){ Wh[0], Wh[1] };
    ha += (v2f){ xa[2], xa[3] } * (v2f){ Wh[2], Wh[3] };
    float acc = ha.x + ha.y;

#pragma unroll
    for (int j = 0; j < 10; j += 2) {
        v2f d2 = { 0.0f, 0.0f };
#pragma unroll
        for (int k = 0; k < 4; ++k) {
            v2f p = { protos[j * 4 + k], protos[(j + 1) * 4 + k] };
            v2f d = (v2f){ xa[k], xa[k] } - p;
            d2 += d * d;
        }
        v2f d2s = d2 * -1.4426950408889634f;        // -log2e
        float kf0 = __builtin_amdgcn_exp2f(d2s.x);  // exp(-d2)
        float kf1 = __builtin_amdgcn_exp2f(d2s.y);
        acc = fmaf(kf0, Wh[4 + j], acc);
        acc = fmaf(kf1, Wh[5 + j], acc);
    }
    // sigmoid
    float e = __builtin_amdgcn_exp2f(acc * -1.4426950408889634f);
    out[tid] = __builtin_amdgcn_rcpf(1.0f + e);
}

extern "C" void kernel_launch(void* const* d_in, const int* in_sizes, int n_in,
                              void* d_out, int out_size, void* d_ws, size_t ws_size,
                              hipStream_t stream) {
    const float* inputs = (const float*)d_in[0];
    Params ps;
    for (int i = 0; i < 15; ++i) ps.p[i] = (const float*)d_in[i + 1];
    float* out = (float*)d_out;
    const int B = in_sizes[0] / 8;
    const int blocks = (B + THREADS - 1) / THREADS;
    qcnn_fused<<<blocks, THREADS, 0, stream>>>(inputs, ps, out, B);
}